// Round 3
// baseline (309.571 us; speedup 1.0000x reference)
//
#include <hip/hip_runtime.h>
#include <hip/hip_cooperative_groups.h>
#include <hip/hip_bf16.h>
#include <cstddef>
#include <cstdint>

namespace cg = cooperative_groups;

typedef float v4f __attribute__((ext_vector_type(4)));
typedef short v8s __attribute__((ext_vector_type(8)));
typedef _Float16 v8h __attribute__((ext_vector_type(8)));

__device__ __forceinline__ uint32_t fbits(float x){ uint32_t u; __builtin_memcpy(&u,&x,4); return u; }
__device__ __forceinline__ float ffrom(uint32_t u){ float f; __builtin_memcpy(&f,&u,4); return f; }
// round-half-up bf16
__device__ __forceinline__ short bf_rh(float x){ return (short)((fbits(x)+0x8000u)>>16); }
__device__ __forceinline__ uint32_t pack_bf_rh(float a, float b){
    uint32_t ua = fbits(a)+0x8000u, ub = fbits(b)+0x8000u;
#if __has_builtin(__builtin_amdgcn_perm)
    return __builtin_amdgcn_perm(ub, ua, 0x07060302u);
#else
    return (ua>>16) | (ub & 0xFFFF0000u);
#endif
}
// fp16 (RNE) stored in a short
__device__ __forceinline__ short f2h(float x){ _Float16 h = (_Float16)x; short s; __builtin_memcpy(&s,&h,2); return s; }
#if __has_builtin(__builtin_amdgcn_exp2f)
#define EXP2(x) __builtin_amdgcn_exp2f(x)
#else
#define EXP2(x) exp2f(x)
#endif

__device__ __forceinline__ void gld16(const void* g, void* l) {
    __builtin_amdgcn_global_load_lds(
        (const __attribute__((address_space(1))) unsigned int*)g,
        (__attribute__((address_space(3))) unsigned int*)l, 16, 0, 0);
}
#define MFMA(a,b,c)  __builtin_amdgcn_mfma_f32_16x16x32_bf16((a),(b),(c),0,0,0)
#define MFMAH(a,b,c) __builtin_amdgcn_mfma_f32_16x16x32_f16((a),(b),(c),0,0,0)

#define LOG2E 1.4426950408889634f

// ===========================================================================
// FALLBACK PIPELINE (round-1 verbatim, known-good at ~149 us)
// ===========================================================================
__global__ __launch_bounds__(256)
void prep_kernel(const float* __restrict__ x,  short* __restrict__ xh,
                 const float* __restrict__ wq, short* __restrict__ wqh,
                 const float* __restrict__ wp, short* __restrict__ wph,
                 const float* __restrict__ rct,
                 const float* __restrict__ fc1w, const float* __restrict__ fc1b,
                 const float* __restrict__ fc2w, const float* __restrict__ fc2b,
                 float* __restrict__ table)
{
    __shared__ float s1[1024];
    __shared__ float sb[512];
    __shared__ float s2[4096];
    int bid = blockIdx.x;
    int tid = threadIdx.x;
    if (bid < 1152) {
        const float* src; short* dh; int base8;
        if (bid < 1024)      { src = x;  dh = xh;  base8 = bid * 256; }
        else if (bid < 1120) { src = wq; dh = wqh; base8 = (bid-1024) * 256; }
        else                 { src = wp; dh = wph; base8 = (bid-1120) * 256; }
        int e0 = (base8 + tid) * 8;
        int m  = e0 >> 8;
        int k  = e0 & 255;
        int kt = k >> 6, c = (k >> 3) & 7;
        float4 f0 = *(const float4*)(src + e0);
        float4 f1 = *(const float4*)(src + e0 + 4);
        float v[8] = {f0.x,f0.y,f0.z,f0.w,f1.x,f1.y,f1.z,f1.w};
        v8s hi;
        #pragma unroll
        for (int j = 0; j < 8; ++j) hi[j] = f2h(v[j]);
        int dst = m*256 + kt*64 + ((c ^ (m & 7)) << 3);
        *(v8s*)&dh[dst] = hi;
    } else {
        int cbid = bid - 1152;
        for (int i = tid; i < 1024; i += 256) s1[i] = fc1w[i];
        for (int i = tid; i < 512;  i += 256) sb[i] = fc1b[i];
        for (int i = tid; i < 4096; i += 256) s2[i] = fc2w[i];
        __syncthreads();
        int rl = tid >> 2, jp = tid & 3;
        bool ok = rl < 63;
        int r = cbid * 63 + rl;
        float c0 = ok ? rct[2*r]   : 0.f;
        float c1 = ok ? rct[2*r+1] : 0.f;
        float a[8] = {0,0,0,0,0,0,0,0};
        int j0 = jp * 128;
        #pragma unroll 4
        for (int j = j0; j < j0 + 128; ++j) {
            float hv = fmaxf(c0*s1[2*j] + c1*s1[2*j+1] + sb[j], 0.0f);
            #pragma unroll
            for (int hh = 0; hh < 8; ++hh) a[hh] += hv * s2[hh*512 + j];
        }
        #pragma unroll
        for (int hh = 0; hh < 8; ++hh) {
            a[hh] += __shfl_xor(a[hh], 1);
            a[hh] += __shfl_xor(a[hh], 2);
        }
        if (ok && jp == 0) {
            #pragma unroll
            for (int hh = 0; hh < 8; ++hh) table[hh*3969 + r] = a[hh] + fc2b[hh];
        }
    }
}

__global__ __launch_bounds__(256)
void qkv_bias_kernel(const short* __restrict__ xh, const short* __restrict__ wqh,
                     const float* __restrict__ qkvb,
                     short* __restrict__ qh, short* __restrict__ kh,
                     short* __restrict__ vt,
                     const float* __restrict__ qe, const float* __restrict__ temp,
                     const float* __restrict__ tblf, const int* __restrict__ rpi,
                     short* __restrict__ biasM)
{
    __shared__ __align__(16) char smem[49152];
    int bid  = blockIdx.x;
    int tid  = threadIdx.x;
    int w    = tid >> 6;
    int lane = tid & 63;
    int t    = lane & 15;
    int quad = lane >> 4;

    if (bid < 768) {
        short* A0 = (short*)smem;
        short* A1 = A0 + 128*64;
        short* W0 = A1 + 128*64;
        short* W1 = W0 + 64*64;
        int n0 = (bid % 12) * 64, m0 = (bid / 12) * 128;
        int Mw = (w >> 1) * 64, Nw = (w & 1) * 32;

        v4f acc[4][2];
        #pragma unroll
        for (int mt = 0; mt < 4; ++mt)
            #pragma unroll
            for (int nt = 0; nt < 2; ++nt) acc[mt][nt] = (v4f){0,0,0,0};

        int lr8 = lane >> 3, lc8 = lane & 7;
        #pragma unroll 1
        for (int kt2 = 0; kt2 < 2; ++kt2) {
            __syncthreads();
            #pragma unroll
            for (int half = 0; half < 2; ++half) {
                int kt = kt2*2 + half;
                short* Ad = half ? A1 : A0;
                short* Wd = half ? W1 : W0;
                #pragma unroll
                for (int i = 0; i < 4; ++i) {
                    size_t grow = (size_t)(m0 + w*32 + i*8 + lr8) * 256 + kt*64 + lc8*8;
                    gld16(xh + grow, Ad + (w*32 + i*8) * 64);
                }
                #pragma unroll
                for (int i = 0; i < 2; ++i) {
                    size_t grow = (size_t)(n0 + w*16 + i*8 + lr8) * 256 + kt*64 + lc8*8;
                    gld16(wqh + grow, Wd + (w*16 + i*8) * 64);
                }
            }
            __syncthreads();
            #pragma unroll
            for (int half = 0; half < 2; ++half) {
                const short* As = half ? A1 : A0;
                const short* Ws = half ? W1 : W0;
                #pragma unroll
                for (int kk = 0; kk < 2; ++kk) {
                    int cp = ((kk*4 + quad) ^ (t & 7)) << 3;
                    v8h bh8[2];
                    #pragma unroll
                    for (int nt = 0; nt < 2; ++nt)
                        bh8[nt] = *(const v8h*)&Ws[(Nw + nt*16 + t)*64 + cp];
                    #pragma unroll
                    for (int mt = 0; mt < 4; ++mt) {
                        v8h ah = *(const v8h*)&As[(Mw + mt*16 + t)*64 + cp];
                        #pragma unroll
                        for (int nt = 0; nt < 2; ++nt)
                            acc[mt][nt] = MFMAH(ah, bh8[nt], acc[mt][nt]);
                    }
                }
            }
        }

        #pragma unroll
        for (int nt = 0; nt < 2; ++nt) {
            float bv = qkvb[n0 + Nw + nt*16 + t];
            #pragma unroll
            for (int mt = 0; mt < 4; ++mt)
                #pragma unroll
                for (int r = 0; r < 4; ++r) acc[mt][nt][r] += bv;
        }

        int which = n0 >> 8;
        if (which < 2) {
            int head = ((n0 + Nw) >> 5) & 7;
            float scale = 0.f;
            if (which == 0)
                scale = log1pf(__expf(temp[head])) * 10.0f;
            #pragma unroll
            for (int mt = 0; mt < 4; ++mt)
                #pragma unroll
                for (int r = 0; r < 4; ++r) {
                    float a0 = acc[mt][0][r], a1 = acc[mt][1][r];
                    float s = a0*a0 + a1*a1;
                    s += __shfl_xor(s, 1); s += __shfl_xor(s, 2);
                    s += __shfl_xor(s, 4); s += __shfl_xor(s, 8);
                    float inv = 1.0f / fmaxf(sqrtf(s), 1e-12f);
                    int m = m0 + Mw + mt*16 + quad*4 + r;
                    int b = m >> 10, nrow = m & 1023;
                    if (which == 0) {
                        size_t rowoff = (((size_t)b*8 + head)*1024 + nrow) * 32;
                        #pragma unroll
                        for (int nt = 0; nt < 2; ++nt) {
                            int d = nt*16 + t;
                            float val = (acc[mt][nt][r] * inv + qe[head*32 + d]) * scale;
                            qh[rowoff + d] = f2h(val);
                        }
                    } else {
                        int kk = nrow & 63;
                        int pp = (kk & 3)*16 + (kk >> 2);
                        int prow = (nrow & ~63) | pp;
                        int swk = (kk >> 3) & 3;
                        size_t rowoff = (((size_t)b*8 + head)*1024 + prow) * 32;
                        #pragma unroll
                        for (int nt = 0; nt < 2; ++nt) {
                            int d = nt*16 + t;
                            int dpos = (((d >> 3) ^ swk) << 3) | (d & 7);
                            kh[rowoff + dpos] = f2h(acc[mt][nt][r] * inv);
                        }
                    }
                }
        } else {
            __syncthreads();
            short* VT = (short*)smem;        // [64][136]
            #pragma unroll
            for (int mt = 0; mt < 4; ++mt)
                #pragma unroll
                for (int nt = 0; nt < 2; ++nt) {
                    int cl = Nw + nt*16 + t;
                    #pragma unroll
                    for (int r = 0; r < 4; ++r) {
                        int rl = Mw + mt*16 + quad*4 + r;
                        VT[cl*136 + rl] = bf_rh(acc[mt][nt][r]);
                    }
                }
            __syncthreads();
            int b = m0 >> 10;
            int keybase = m0 & 1023;
            int headbase = ((n0 - 512) >> 5) & 7;
            int cl = tid >> 2;
            int dim = cl & 31;
            int hd  = headbase + (cl >> 5);
            size_t obase = (((size_t)b*8 + hd)*32 + dim) * 1024 + keybase;
            #pragma unroll
            for (int pz = 0; pz < 4; ++pz) {
                int ci  = (tid & 3) * 4 + pz;
                int ktl = ci >> 3, c = ci & 7;
                v8s val = *(const v8s*)&VT[cl*136 + ktl*64 + c*8];
                *(v8s*)&vt[obase + ktl*64 + ((c ^ (dim & 7)) << 3)] = val;
            }
        }
    } else {
        float* tb = (float*)smem;            // [3969]
        int b2  = bid - 768;
        int h2  = b2 & 7;
        int q16 = b2 >> 3;
        for (int i = tid; i < 3969; i += 256) tb[i] = tblf[h2*3969 + i] * LOG2E;
        __syncthreads();
        int row0 = q16*16 + quad*4;
        #pragma unroll 1
        for (int kk = 0; kk < 4; ++kk) {
            int kt = w*4 + kk;
            #pragma unroll
            for (int g = 0; g < 4; ++g) {
                float o[4];
                #pragma unroll
                for (int r = 0; r < 4; ++r)
                    o[r] = tb[rpi[(size_t)(row0 + r)*1024 + kt*64 + 4*t + g]];
                uint2 pk;
                pk.x = pack_bf_rh(o[0], o[1]);
                pk.y = pack_bf_rh(o[2], o[3]);
                size_t base = ((((size_t)(h2*64 + q16)*16 + kt)*4 + g)*64 + lane)*4;
                *(uint2*)(biasM + base) = pk;
            }
        }
    }
}

__global__ __launch_bounds__(512)
void attn_mfma(const short* __restrict__ qh, const short* __restrict__ kh,
               const short* __restrict__ vt,  const short* __restrict__ biasM,
               short* __restrict__ yh)
{
    __shared__ __align__(16) short Kh_s[2][2048];
    __shared__ __align__(16) short Vt_s[2][2048];
    __shared__ __align__(16) short Ps[8][16][68];

    int bh  = blockIdx.x & 63;
    int qt  = blockIdx.x >> 6;
    int h   = bh & 7;
    int b   = bh >> 3;
    int tid = threadIdx.x;
    int w    = tid >> 6;
    int lane = tid & 63;
    int t    = lane & 15;
    int quad = lane >> 4;

    size_t qoff = ((size_t)bh*1024 + qt*128 + w*16 + t) * 32 + quad*8;
    v8h qf = *(const v8h*)(qh + qoff);

    v4f Oacc[2] = {{0,0,0,0},{0,0,0,0}};
    float lsum[4] = {0,0,0,0};

    size_t kgbase = (size_t)bh * 32768;
    const short* bmb = biasM + ((size_t)(h*64 + qt*8 + w) * 16) * 1024 + lane*4;
    int qrow0 = qt*128 + w*16 + quad*4;
    int swzS = (quad ^ ((t >> 1) & 3)) << 3;
    int lr8 = lane >> 3, lc8 = lane & 7;

    if (w < 4)
        gld16(kh + kgbase + w*512 + lane*8, &Kh_s[0][w*512]);
    else
        gld16(vt + kgbase + (size_t)((w-4)*8 + lr8)*1024 + lc8*8, &Vt_s[0][(w-4)*512]);
    uint2 curb[4];
    #pragma unroll
    for (int g = 0; g < 4; ++g) curb[g] = *(const uint2*)(bmb + g*256);

    #pragma unroll 1
    for (int kt = 0; kt < 16; ++kt) {
        int cur = kt & 1;
        __syncthreads();
        uint2 nxtb[4];
        if (kt < 15) {
            int nkt = kt + 1, nb = cur ^ 1;
            if (w < 4)
                gld16(kh + kgbase + (size_t)nkt*2048 + w*512 + lane*8, &Kh_s[nb][w*512]);
            else
                gld16(vt + kgbase + (size_t)((w-4)*8 + lr8)*1024 + nkt*64 + lc8*8,
                      &Vt_s[nb][(w-4)*512]);
            const short* bp = bmb + (size_t)nkt*1024;
            #pragma unroll
            for (int g = 0; g < 4; ++g) nxtb[g] = *(const uint2*)(bp + g*256);
        }

        v4f S[4];
        #pragma unroll
        for (int g = 0; g < 4; ++g) {
            v8h kb = *(const v8h*)&Kh_s[cur][(g*16 + t)*32 + swzS];
            v4f c;
            c[0] = ffrom(curb[g].x << 16);
            c[1] = ffrom(curb[g].x & 0xFFFF0000u);
            c[2] = ffrom(curb[g].y << 16);
            c[3] = ffrom(curb[g].y & 0xFFFF0000u);
            S[g] = MFMAH(qf, kb, c);
        }

        #pragma unroll
        for (int r = 0; r < 4; ++r) {
            float p0 = EXP2(S[0][r]);
            float p1 = EXP2(S[1][r]);
            float p2 = EXP2(S[2][r]);
            float p3 = EXP2(S[3][r]);
            lsum[r] += (p0 + p1) + (p2 + p3);
            uint2 pk;
            pk.x = pack_bf_rh(p0, p1);
            pk.y = pack_bf_rh(p2, p3);
            *(uint2*)&Ps[w][quad*4 + r][t*4] = pk;
        }

        #pragma unroll
        for (int ks = 0; ks < 2; ++ks) {
            v8s pf = *(const v8s*)&Ps[w][t][ks*32 + quad*8];
            int vsw = ((ks*4 + quad) ^ (t & 7)) << 3;
            #pragma unroll
            for (int g = 0; g < 2; ++g) {
                v8s vf = *(const v8s*)&Vt_s[cur][(g*16 + t)*64 + vsw];
                Oacc[g] = MFMA(pf, vf, Oacc[g]);
            }
        }
        #pragma unroll
        for (int g = 0; g < 4; ++g) curb[g] = nxtb[g];
    }

    #pragma unroll
    for (int r = 0; r < 4; ++r) {
        float l = lsum[r];
        l += __shfl_xor(l, 1); l += __shfl_xor(l, 2);
        l += __shfl_xor(l, 4); l += __shfl_xor(l, 8);
        float inv = 1.0f / l;
        int qrow = qrow0 + r;
        int m = b*1024 + qrow;
        size_t mbase = (size_t)m * 256;
        int mk = m & 7;
        #pragma unroll
        for (int g = 0; g < 2; ++g) {
            float o = Oacc[g][r] * inv;
            int c = h*4 + g*2 + (t >> 3);
            int chp = ((c ^ mk) << 3) | (t & 7);
            yh[mbase + chp] = f2h(o);
        }
    }
}

__global__ __launch_bounds__(256)
void gemm_proj(const short* __restrict__ Ah_g, const short* __restrict__ Wh_g,
               const float* __restrict__ bias, float* __restrict__ C, int N)
{
    __shared__ __align__(16) short As[2][4096];
    __shared__ __align__(16) short Ws[2][4096];

    int tid  = threadIdx.x;
    int w    = tid >> 6;
    int lane = tid & 63;
    int t    = lane & 15;
    int quad = lane >> 4;
    int m0 = blockIdx.y * 64, n0 = blockIdx.x * 64;
    int Mw = (w >> 1) * 32, Nw = (w & 1) * 32;

    v4f acc[2][2];
    #pragma unroll
    for (int mt = 0; mt < 2; ++mt)
        #pragma unroll
        for (int nt = 0; nt < 2; ++nt) acc[mt][nt] = (v4f){0,0,0,0};

    int lr8 = lane >> 3, lc8 = lane & 7;
    #pragma unroll 1
    for (int kt2 = 0; kt2 < 2; ++kt2) {
        __syncthreads();
        #pragma unroll
        for (int half = 0; half < 2; ++half) {
            int kt = kt2*2 + half;
            #pragma unroll
            for (int i = 0; i < 2; ++i) {
                size_t grow = (size_t)(m0 + w*16 + i*8 + lr8) * 256 + kt*64 + lc8*8;
                gld16(Ah_g + grow, &As[half][(w*16 + i*8) * 64]);
            }
            #pragma unroll
            for (int i = 0; i < 2; ++i) {
                size_t grow = (size_t)(n0 + w*16 + i*8 + lr8) * 256 + kt*64 + lc8*8;
                gld16(Wh_g + grow, &Ws[half][(w*16 + i*8) * 64]);
            }
        }
        __syncthreads();
        #pragma unroll
        for (int half = 0; half < 2; ++half) {
            #pragma unroll
            for (int kk = 0; kk < 2; ++kk) {
                int cp = ((kk*4 + quad) ^ (t & 7)) << 3;
                v8h bh8[2];
                #pragma unroll
                for (int nt = 0; nt < 2; ++nt)
                    bh8[nt] = *(const v8h*)&Ws[half][(Nw + nt*16 + t)*64 + cp];
                #pragma unroll
                for (int mt = 0; mt < 2; ++mt) {
                    v8h ah = *(const v8h*)&As[half][(Mw + mt*16 + t)*64 + cp];
                    #pragma unroll
                    for (int nt = 0; nt < 2; ++nt)
                        acc[mt][nt] = MFMAH(ah, bh8[nt], acc[mt][nt]);
                }
            }
        }
    }

    #pragma unroll
    for (int nt = 0; nt < 2; ++nt) {
        float bv = bias[n0 + Nw + nt*16 + t];
        #pragma unroll
        for (int mt = 0; mt < 2; ++mt)
            #pragma unroll
            for (int r = 0; r < 4; ++r) acc[mt][nt][r] += bv;
    }
    #pragma unroll
    for (int mt = 0; mt < 2; ++mt)
        #pragma unroll
        for (int r = 0; r < 4; ++r) {
            int m = m0 + Mw + mt*16 + quad*4 + r;
            #pragma unroll
            for (int nt = 0; nt < 2; ++nt)
                C[(size_t)m * N + n0 + Nw + nt*16 + t] = acc[mt][nt][r];
        }
}

// ===========================================================================
// MEGA persistent cooperative kernel: grid-stride phases separated by
// cg::this_grid().sync() (vendor-validated cross-XCD fences). Works for any
// grid size G (launched with G = min(512, occupancy-capacity)).
// ===========================================================================
__global__ __launch_bounds__(256, 2)
void mega(const float* __restrict__ x,    const float* __restrict__ wq,
          const float* __restrict__ wp,   const float* __restrict__ rct,
          const float* __restrict__ fc1w, const float* __restrict__ fc1b,
          const float* __restrict__ fc2w, const float* __restrict__ fc2b,
          const float* __restrict__ qkvb, const float* __restrict__ qe,
          const float* __restrict__ temp, const int*   __restrict__ rpi,
          const float* __restrict__ projb, float* __restrict__ out,
          short* __restrict__ xh,  short* __restrict__ wqh,
          short* __restrict__ wph, float* __restrict__ tblf,
          short* __restrict__ qh,  short* __restrict__ kh,
          short* __restrict__ vt,  short* __restrict__ biasM)
{
    cg::grid_group grid = cg::this_grid();
    __shared__ __align__(16) char smem[49152];
    int bid  = blockIdx.x;
    int G    = gridDim.x;
    int tid  = threadIdx.x;
    int w    = tid >> 6;        // wave 0..3
    int lane = tid & 63;
    int t    = lane & 15;
    int quad = lane >> 4;
    int lr8  = lane >> 3, lc8 = lane & 7;

    // ---------------- phase 0: prep ----------------
    for (int u = bid; u < 1215; u += G) {
        if (u < 1152) {
            const float* src; short* dh; int base8;
            if (u < 1024)      { src = x;  dh = xh;  base8 = u * 256; }
            else if (u < 1120) { src = wq; dh = wqh; base8 = (u-1024) * 256; }
            else               { src = wp; dh = wph; base8 = (u-1120) * 256; }
            int e0 = (base8 + tid) * 8;
            int m  = e0 >> 8;
            int k  = e0 & 255;
            int kt = k >> 6, c = (k >> 3) & 7;
            float4 f0 = *(const float4*)(src + e0);
            float4 f1 = *(const float4*)(src + e0 + 4);
            float v[8] = {f0.x,f0.y,f0.z,f0.w,f1.x,f1.y,f1.z,f1.w};
            v8s hi;
            #pragma unroll
            for (int j = 0; j < 8; ++j) hi[j] = f2h(v[j]);
            int dst = m*256 + kt*64 + ((c ^ (m & 7)) << 3);
            *(v8s*)&dh[dst] = hi;
        } else {
            __syncthreads();               // protect LDS reuse across units
            float* s1 = (float*)smem;      // 1024 f
            float* sb = s1 + 1024;         // 512 f
            float* s2 = sb + 512;          // 4096 f
            int cbid = u - 1152;
            for (int i = tid; i < 1024; i += 256) s1[i] = fc1w[i];
            for (int i = tid; i < 512;  i += 256) sb[i] = fc1b[i];
            for (int i = tid; i < 4096; i += 256) s2[i] = fc2w[i];
            __syncthreads();
            int rl = tid >> 2, jp = tid & 3;
            bool ok = rl < 63;
            int r = cbid * 63 + rl;
            float c0 = ok ? rct[2*r]   : 0.f;
            float c1 = ok ? rct[2*r+1] : 0.f;
            float a[8] = {0,0,0,0,0,0,0,0};
            int j0 = jp * 128;
            #pragma unroll 4
            for (int j = j0; j < j0 + 128; ++j) {
                float hv = fmaxf(c0*s1[2*j] + c1*s1[2*j+1] + sb[j], 0.0f);
                #pragma unroll
                for (int hh = 0; hh < 8; ++hh) a[hh] += hv * s2[hh*512 + j];
            }
            #pragma unroll
            for (int hh = 0; hh < 8; ++hh) {
                a[hh] += __shfl_xor(a[hh], 1);
                a[hh] += __shfl_xor(a[hh], 2);
            }
            if (ok && jp == 0) {
                #pragma unroll
                for (int hh = 0; hh < 8; ++hh) tblf[hh*3969 + r] = a[hh] + fc2b[hh];
            }
        }
    }

    grid.sync();

    // ---------------- phase 1: qkv GEMM + biasM ----------------
    for (int u = bid; u < 1280; u += G) {
        __syncthreads();   // protect LDS reuse between sequential units
        if (u < 768) {
            short* A0 = (short*)smem;          // [128][64] fp16, k-tile even
            short* A1 = A0 + 128*64;
            short* W0 = A1 + 128*64;           // [64][64]
            short* W1 = W0 + 64*64;
            int n0 = (u % 12) * 64, m0 = (u / 12) * 128;
            int Mw = (w >> 1) * 64, Nw = (w & 1) * 32;

            v4f acc[4][2];
            #pragma unroll
            for (int mt = 0; mt < 4; ++mt)
                #pragma unroll
                for (int nt = 0; nt < 2; ++nt) acc[mt][nt] = (v4f){0,0,0,0};

            #pragma unroll 1
            for (int kt2 = 0; kt2 < 2; ++kt2) {
                __syncthreads();
                #pragma unroll
                for (int half = 0; half < 2; ++half) {
                    int kt = kt2*2 + half;
                    short* Ad = half ? A1 : A0;
                    short* Wd = half ? W1 : W0;
                    #pragma unroll
                    for (int i = 0; i < 4; ++i) {
                        size_t grow = (size_t)(m0 + w*32 + i*8 + lr8) * 256 + kt*64 + lc8*8;
                        gld16(xh + grow, Ad + (w*32 + i*8) * 64);
                    }
                    #pragma unroll
                    for (int i = 0; i < 2; ++i) {
                        size_t grow = (size_t)(n0 + w*16 + i*8 + lr8) * 256 + kt*64 + lc8*8;
                        gld16(wqh + grow, Wd + (w*16 + i*8) * 64);
                    }
                }
                __syncthreads();
                #pragma unroll
                for (int half = 0; half < 2; ++half) {
                    const short* As = half ? A1 : A0;
                    const short* Ws = half ? W1 : W0;
                    #pragma unroll
                    for (int kk = 0; kk < 2; ++kk) {
                        int cp = ((kk*4 + quad) ^ (t & 7)) << 3;
                        v8h bh8[2];
                        #pragma unroll
                        for (int nt = 0; nt < 2; ++nt)
                            bh8[nt] = *(const v8h*)&Ws[(Nw + nt*16 + t)*64 + cp];
                        #pragma unroll
                        for (int mt = 0; mt < 4; ++mt) {
                            v8h ah = *(const v8h*)&As[(Mw + mt*16 + t)*64 + cp];
                            #pragma unroll
                            for (int nt = 0; nt < 2; ++nt)
                                acc[mt][nt] = MFMAH(ah, bh8[nt], acc[mt][nt]);
                        }
                    }
                }
            }

            #pragma unroll
            for (int nt = 0; nt < 2; ++nt) {
                float bv = qkvb[n0 + Nw + nt*16 + t];
                #pragma unroll
                for (int mt = 0; mt < 4; ++mt)
                    #pragma unroll
                    for (int r = 0; r < 4; ++r) acc[mt][nt][r] += bv;
            }

            int which = n0 >> 8;
            if (which < 2) {
                int head = ((n0 + Nw) >> 5) & 7;
                float scale = 0.f;
                if (which == 0)
                    scale = log1pf(__expf(temp[head])) * 10.0f;
                #pragma unroll
                for (int mt = 0; mt < 4; ++mt)
                    #pragma unroll
                    for (int r = 0; r < 4; ++r) {
                        float a0 = acc[mt][0][r], a1 = acc[mt][1][r];
                        float s = a0*a0 + a1*a1;
                        s += __shfl_xor(s, 1); s += __shfl_xor(s, 2);
                        s += __shfl_xor(s, 4); s += __shfl_xor(s, 8);
                        float inv = 1.0f / fmaxf(sqrtf(s), 1e-12f);
                        int m = m0 + Mw + mt*16 + quad*4 + r;
                        int b = m >> 10, nrow = m & 1023;
                        if (which == 0) {
                            size_t rowoff = (((size_t)b*8 + head)*1024 + nrow) * 32;
                            #pragma unroll
                            for (int nt = 0; nt < 2; ++nt) {
                                int d = nt*16 + t;
                                float val = (acc[mt][nt][r] * inv + qe[head*32 + d]) * scale;
                                qh[rowoff + d] = f2h(val);
                            }
                        } else {
                            int kk = nrow & 63;
                            int pp = (kk & 3)*16 + (kk >> 2);
                            int prow = (nrow & ~63) | pp;
                            int swk = (kk >> 3) & 3;
                            size_t rowoff = (((size_t)b*8 + head)*1024 + prow) * 32;
                            #pragma unroll
                            for (int nt = 0; nt < 2; ++nt) {
                                int d = nt*16 + t;
                                int dpos = (((d >> 3) ^ swk) << 3) | (d & 7);
                                kh[rowoff + dpos] = f2h(acc[mt][nt][r] * inv);
                            }
                        }
                    }
            } else {
                __syncthreads();
                short* VT = (short*)smem;        // [64][136]
                #pragma unroll
                for (int mt = 0; mt < 4; ++mt)
                    #pragma unroll
                    for (int nt = 0; nt < 2; ++nt) {
                        int cl = Nw + nt*16 + t;
                        #pragma unroll
                        for (int r = 0; r < 4; ++r) {
                            int rl = Mw + mt*16 + quad*4 + r;
                            VT[cl*136 + rl] = bf_rh(acc[mt][nt][r]);
                        }
                    }
                __syncthreads();
                int b = m0 >> 10;
                int keybase = m0 & 1023;
                int headbase = ((n0 - 512) >> 5) & 7;
                int cl = tid >> 2;
                int dim = cl & 31;
                int hd  = headbase + (cl >> 5);
                size_t obase = (((size_t)b*8 + hd)*32 + dim) * 1024 + keybase;
                #pragma unroll
                for (int pz = 0; pz < 4; ++pz) {
                    int ci  = (tid & 3) * 4 + pz;
                    int ktl = ci >> 3, c = ci & 7;
                    v8s val = *(const v8s*)&VT[cl*136 + ktl*64 + c*8];
                    *(v8s*)&vt[obase + ktl*64 + ((c ^ (dim & 7)) << 3)] = val;
                }
            }
        } else {
            float* tb = (float*)smem;            // [3969]
            int b2  = u - 768;
            int h2  = b2 & 7;
            int q16 = b2 >> 3;
            for (int i = tid; i < 3969; i += 256) tb[i] = tblf[h2*3969 + i] * LOG2E;
            __syncthreads();
            int row0 = q16*16 + quad*4;
            #pragma unroll 1
            for (int kk = 0; kk < 4; ++kk) {
                int kt = w*4 + kk;
                #pragma unroll
                for (int g = 0; g < 4; ++g) {
                    float o[4];
                    #pragma unroll
                    for (int r = 0; r < 4; ++r)
                        o[r] = tb[rpi[(size_t)(row0 + r)*1024 + kt*64 + 4*t + g]];
                    uint2 pk;
                    pk.x = pack_bf_rh(o[0], o[1]);
                    pk.y = pack_bf_rh(o[2], o[3]);
                    size_t base = ((((size_t)(h2*64 + q16)*16 + kt)*4 + g)*64 + lane)*4;
                    *(uint2*)(biasM + base) = pk;
                }
            }
        }
    }

    grid.sync();

    // ---------------- phase 2: attention (4-wave, 64-row Q-tile) ----------------
    for (int u = bid; u < 1024; u += G) {
        int bh  = u & 63;
        int qt2 = u >> 6;          // 0..15
        int h   = bh & 7;
        int b   = bh >> 3;
        short* Kh  = (short*)smem;           // [2][2048] fp16  ([64][32] per buf)
        short* Vts = Kh + 4096;              // [2][2048] bf16  ([32][64] per buf)
        short* Psb = Vts + 4096;             // [4][16][68] bf16 per-wave P

        size_t qoff = ((size_t)bh*1024 + qt2*64 + w*16 + t) * 32 + quad*8;
        v8h qf = *(const v8h*)(qh + qoff);

        v4f Oacc[2] = {{0,0,0,0},{0,0,0,0}};
        float lsum[4] = {0,0,0,0};

        size_t kgbase = (size_t)bh * 32768;
        const short* bmb = biasM + ((size_t)(h*64 + qt2*4 + w) * 16) * 1024 + lane*4;
        int qrow0 = qt2*64 + w*16 + quad*4;
        int swzS = (quad ^ ((t >> 1) & 3)) << 3;

        __syncthreads();   // protect LDS reuse from previous unit/phase
        if (w < 2) {
            gld16(kh + kgbase + (w*2+0)*512 + lane*8, &Kh[(w*2+0)*512]);
            gld16(kh + kgbase + (w*2+1)*512 + lane*8, &Kh[(w*2+1)*512]);
        } else {
            int v0 = w - 2;
            gld16(vt + kgbase + (size_t)(v0*16 + lr8)*1024 + lc8*8,     &Vts[(v0*2+0)*512]);
            gld16(vt + kgbase + (size_t)(v0*16 + 8 + lr8)*1024 + lc8*8, &Vts[(v0*2+1)*512]);
        }
        uint2 curb[4];
        #pragma unroll
        for (int g = 0; g < 4; ++g) curb[g] = *(const uint2*)(bmb + g*256);

        #pragma unroll 1
        for (int kt = 0; kt < 16; ++kt) {
            int cur = kt & 1;
            __syncthreads();
            uint2 nxtb[4];
            if (kt < 15) {
                int nkt = kt + 1, nb = cur ^ 1;
                if (w < 2) {
                    gld16(kh + kgbase + (size_t)nkt*2048 + (w*2+0)*512 + lane*8,
                          &Kh[nb*2048 + (w*2+0)*512]);
                    gld16(kh + kgbase + (size_t)nkt*2048 + (w*2+1)*512 + lane*8,
                          &Kh[nb*2048 + (w*2+1)*512]);
                } else {
                    int v0 = w - 2;
                    gld16(vt + kgbase + (size_t)(v0*16 + lr8)*1024 + nkt*64 + lc8*8,
                          &Vts[nb*2048 + (v0*2+0)*512]);
                    gld16(vt + kgbase + (size_t)(v0*16 + 8 + lr8)*1024 + nkt*64 + lc8*8,
                          &Vts[nb*2048 + (v0*2+1)*512]);
                }
                const short* bp = bmb + (size_t)nkt*1024;
                #pragma unroll
                for (int g = 0; g < 4; ++g) nxtb[g] = *(const uint2*)(bp + g*256);
            }

            v4f S[4];
            #pragma unroll
            for (int g = 0; g < 4; ++g) {
                v8h kb = *(const v8h*)&Kh[cur*2048 + (g*16 + t)*32 + swzS];
                v4f c;
                c[0] = ffrom(curb[g].x << 16);
                c[1] = ffrom(curb[g].x & 0xFFFF0000u);
                c[2] = ffrom(curb[g].y << 16);
                c[3] = ffrom(curb[g].y & 0xFFFF0000u);
                S[g] = MFMAH(qf, kb, c);
            }

            #pragma unroll
            for (int r = 0; r < 4; ++r) {
                float p0 = EXP2(S[0][r]);
                float p1 = EXP2(S[1][r]);
                float p2 = EXP2(S[2][r]);
                float p3 = EXP2(S[3][r]);
                lsum[r] += (p0 + p1) + (p2 + p3);
                uint2 pk;
                pk.x = pack_bf_rh(p0, p1);
                pk.y = pack_bf_rh(p2, p3);
                *(uint2*)&Psb[(w*16 + quad*4 + r)*68 + t*4] = pk;
            }

            #pragma unroll
            for (int ks = 0; ks < 2; ++ks) {
                v8s pf = *(const v8s*)&Psb[(w*16 + t)*68 + ks*32 + quad*8];
                int vsw = ((ks*4 + quad) ^ (t & 7)) << 3;
                #pragma unroll
                for (int g = 0; g < 2; ++g) {
                    v8s vf = *(const v8s*)&Vts[cur*2048 + (g*16 + t)*64 + vsw];
                    Oacc[g] = MFMA(pf, vf, Oacc[g]);
                }
            }
            #pragma unroll
            for (int g = 0; g < 4; ++g) curb[g] = nxtb[g];
        }

        #pragma unroll
        for (int r = 0; r < 4; ++r) {
            float l = lsum[r];
            l += __shfl_xor(l, 1); l += __shfl_xor(l, 2);
            l += __shfl_xor(l, 4); l += __shfl_xor(l, 8);
            float inv = 1.0f / l;
            int qrow = qrow0 + r;
            int m = b*1024 + qrow;
            size_t mbase = (size_t)m * 256;
            int mk = m & 7;
            #pragma unroll
            for (int g = 0; g < 2; ++g) {
                float o = Oacc[g][r] * inv;
                int c = h*4 + g*2 + (t >> 3);
                int chp = ((c ^ mk) << 3) | (t & 7);
                xh[mbase + chp] = f2h(o);
            }
        }
    }

    grid.sync();

    // ---------------- phase 3: output projection ----------------
    for (int u = bid; u < 512; u += G) {
        int m0 = (u >> 2) * 64, n0 = (u & 3) * 64;
        short* As = (short*)smem;           // [2][4096] fp16
        short* Ws = As + 8192;

        int Mw = (w >> 1) * 32, Nw = (w & 1) * 32;

        v4f acc[2][2];
        #pragma unroll
        for (int mt = 0; mt < 2; ++mt)
            #pragma unroll
            for (int nt = 0; nt < 2; ++nt) acc[mt][nt] = (v4f){0,0,0,0};

        #pragma unroll 1
        for (int kt2 = 0; kt2 < 2; ++kt2) {
            __syncthreads();
            #pragma unroll
            for (int half = 0; half < 2; ++half) {
                int kt = kt2*2 + half;
                #pragma unroll
                for (int i = 0; i < 2; ++i) {
                    size_t grow = (size_t)(m0 + w*16 + i*8 + lr8) * 256 + kt*64 + lc8*8;
                    gld16(xh + grow, As + half*4096 + (w*16 + i*8) * 64);
                }
                #pragma unroll
                for (int i = 0; i < 2; ++i) {
                    size_t grow = (size_t)(n0 + w*16 + i*8 + lr8) * 256 + kt*64 + lc8*8;
                    gld16(wph + grow, Ws + half*4096 + (w*16 + i*8) * 64);
                }
            }
            __syncthreads();
            #pragma unroll
            for (int half = 0; half < 2; ++half) {
                #pragma unroll
                for (int kk = 0; kk < 2; ++kk) {
                    int cp = ((kk*4 + quad) ^ (t & 7)) << 3;
                    v8h bh8[2];
                    #pragma unroll
                    for (int nt = 0; nt < 2; ++nt)
                        bh8[nt] = *(const v8h*)&Ws[half*4096 + (Nw + nt*16 + t)*64 + cp];
                    #pragma unroll
                    for (int mt = 0; mt < 2; ++mt) {
                        v8h ah = *(const v8h*)&As[half*4096 + (Mw + mt*16 + t)*64 + cp];
                        #pragma unroll
                        for (int nt = 0; nt < 2; ++nt)
                            acc[mt][nt] = MFMAH(ah, bh8[nt], acc[mt][nt]);
                    }
                }
            }
        }

        #pragma unroll
        for (int nt = 0; nt < 2; ++nt) {
            float bv = projb[n0 + Nw + nt*16 + t];
            #pragma unroll
            for (int mt = 0; mt < 2; ++mt)
                #pragma unroll
                for (int r = 0; r < 4; ++r) acc[mt][nt][r] += bv;
        }
        #pragma unroll
        for (int mt = 0; mt < 2; ++mt)
            #pragma unroll
            for (int r = 0; r < 4; ++r) {
                int m = m0 + Mw + mt*16 + quad*4 + r;
                #pragma unroll
                for (int nt = 0; nt < 2; ++nt)
                    out[(size_t)m * 256 + n0 + Nw + nt*16 + t] = acc[mt][nt][r];
            }
    }
}

// ---------------------------------------------------------------------------
extern "C" void kernel_launch(void* const* d_in, const int* in_sizes, int n_in,
                              void* d_out, int out_size, void* d_ws, size_t ws_size,
                              hipStream_t stream)
{
    const float* x     = (const float*)d_in[0];
    const int*   rpi   = (const int*)d_in[3];
    const float* rct   = (const float*)d_in[4];
    const float* qkvw  = (const float*)d_in[5];
    const float* qkvb  = (const float*)d_in[6];
    const float* qe    = (const float*)d_in[7];
    const float* temp  = (const float*)d_in[8];
    const float* projw = (const float*)d_in[9];
    const float* projb = (const float*)d_in[10];
    const float* fc1w  = (const float*)d_in[11];
    const float* fc1b  = (const float*)d_in[12];
    const float* fc2w  = (const float*)d_in[13];
    const float* fc2b  = (const float*)d_in[14];

    char* p = (char*)d_ws;
    float* tblf  = (float*)p;  p += 131072;
    short* xh    = (short*)p;  p += 4194304;   // reused as y (fp16) after attn
    short* wqh   = (short*)p;  p += 393216;
    short* wph   = (short*)p;  p += 131072;
    short* qh    = (short*)p;  p += 4194304;
    short* kh    = (short*)p;  p += 4194304;
    short* vt    = (short*)p;  p += 4194304;
    short* biasM = (short*)p;  p += 16777216;
    float* out   = (float*)d_out;

    // One-time coop-capacity probe (host-side queries only; capture-safe).
    static int coop_grid = -1;   // -1 unknown, 0 disabled, >0 grid size
    if (coop_grid == -1) {
        int nb = 0, cus = 0, dev = 0;
        if (hipOccupancyMaxActiveBlocksPerMultiprocessor(
                &nb, (const void*)mega, 256, 0) != hipSuccess) nb = 0;
        hipGetDevice(&dev);
        hipDeviceProp_t prop;
        if (hipGetDeviceProperties(&prop, dev) == hipSuccess)
            cus = prop.multiProcessorCount;
        long cap = (long)nb * (long)cus;
        coop_grid = (cap >= 512) ? 512 : (cap >= 64 ? (int)cap : 0);
    }

    bool launched = false;
    if (coop_grid > 0) {
        void* args[] = {
            (void*)&x,    (void*)&qkvw, (void*)&projw, (void*)&rct,
            (void*)&fc1w, (void*)&fc1b, (void*)&fc2w,  (void*)&fc2b,
            (void*)&qkvb, (void*)&qe,   (void*)&temp,  (void*)&rpi,
            (void*)&projb,(void*)&out,
            (void*)&xh,   (void*)&wqh,  (void*)&wph,   (void*)&tblf,
            (void*)&qh,   (void*)&kh,   (void*)&vt,    (void*)&biasM
        };
        hipError_t e = hipLaunchCooperativeKernel((const void*)mega,
                                                  dim3(coop_grid), dim3(256),
                                                  args, 0, stream);
        if (e == hipSuccess) launched = true;
        else coop_grid = 0;   // never retry in this process
    }

    if (!launched) {
        // known-good 4-kernel pipeline (round-1, ~149 us)
        prep_kernel<<<1215, 256, 0, stream>>>(x, xh, qkvw, wqh, projw, wph,
                                              rct, fc1w, fc1b, fc2w, fc2b, tblf);
        qkv_bias_kernel<<<1280, 256, 0, stream>>>(xh, wqh, qkvb, qh, kh, vt,
                                                  qe, temp, tblf, rpi, biasM);
        attn_mfma<<<512, 512, 0, stream>>>(qh, kh, vt, biasM, xh);
        dim3 g2(256/64, 8192/64);
        gemm_proj<<<g2, 256, 0, stream>>>(xh, wph, projb, out, 256);
    }
}

// Round 4
// 148.445 us; speedup vs baseline: 2.0854x; 2.0854x over previous
//
#include <hip/hip_runtime.h>
#include <hip/hip_bf16.h>
#include <cstddef>
#include <cstdint>

typedef float v4f __attribute__((ext_vector_type(4)));
typedef short v8s __attribute__((ext_vector_type(8)));
typedef _Float16 v8h __attribute__((ext_vector_type(8)));

__device__ __forceinline__ uint32_t fbits(float x){ uint32_t u; __builtin_memcpy(&u,&x,4); return u; }
__device__ __forceinline__ float ffrom(uint32_t u){ float f; __builtin_memcpy(&f,&u,4); return f; }
// round-half-up bf16
__device__ __forceinline__ short bf_rh(float x){ return (short)((fbits(x)+0x8000u)>>16); }
__device__ __forceinline__ uint32_t pack_bf_rh(float a, float b){
    uint32_t ua = fbits(a)+0x8000u, ub = fbits(b)+0x8000u;
#if __has_builtin(__builtin_amdgcn_perm)
    return __builtin_amdgcn_perm(ub, ua, 0x07060302u);
#else
    return (ua>>16) | (ub & 0xFFFF0000u);
#endif
}
// fp16 (RNE) stored in a short
__device__ __forceinline__ short f2h(float x){ _Float16 h = (_Float16)x; short s; __builtin_memcpy(&s,&h,2); return s; }
#if __has_builtin(__builtin_amdgcn_exp2f)
#define EXP2(x) __builtin_amdgcn_exp2f(x)
#else
#define EXP2(x) exp2f(x)
#endif

__device__ __forceinline__ void gld16(const void* g, void* l) {
    __builtin_amdgcn_global_load_lds(
        (const __attribute__((address_space(1))) unsigned int*)g,
        (__attribute__((address_space(3))) unsigned int*)l, 16, 0, 0);
}
#define MFMA(a,b,c)  __builtin_amdgcn_mfma_f32_16x16x32_bf16((a),(b),(c),0,0,0)
#define MFMAH(a,b,c) __builtin_amdgcn_mfma_f32_16x16x32_f16((a),(b),(c),0,0,0)

#define LOG2E 1.4426950408889634f

// ---------------------------------------------------------------------------
// K1 fused_qkv (927 blocks x 256):
//   blocks   0..62  : CPB MLP -> tblf[8][3969] (pre-scaled by log2e)
//   blocks  63..94  : proj_w fp32 -> fp16 chunk-swizzled (wph)
//   blocks  95..158 : rpi -> packed u16 indices bi[] in MFMA C-frag order
//                     (u64 = 4 rows' indices for one (q16,kt,g,lane))
//   blocks 159..926 : qkv GEMM TM=128 TN=64 BK=128, staging fp32 x / qkv_w
//                     with in-register fp16 convert + write-side XOR swizzle
//                     (LDS image bit-identical to the old gld16-from-xh path);
//                     fused q/k/v epilogues unchanged.
// All four block families are mutually independent -> one launch.
// ---------------------------------------------------------------------------
__global__ __launch_bounds__(256)
void fused_qkv(const float* __restrict__ x,   const float* __restrict__ wq,
               const float* __restrict__ wp,  const float* __restrict__ rct,
               const float* __restrict__ fc1w, const float* __restrict__ fc1b,
               const float* __restrict__ fc2w, const float* __restrict__ fc2b,
               const float* __restrict__ qkvb, const float* __restrict__ qe,
               const float* __restrict__ temp, const int* __restrict__ rpi,
               short* __restrict__ qh, short* __restrict__ kh,
               short* __restrict__ vt, float* __restrict__ tblf,
               short* __restrict__ wph, unsigned long long* __restrict__ bi)
{
    __shared__ __align__(16) char smem[49152];
    int bid  = blockIdx.x;
    int tid  = threadIdx.x;
    int w    = tid >> 6;
    int lane = tid & 63;
    int t    = lane & 15;
    int quad = lane >> 4;
    int lr8  = lane >> 3, lc8 = lane & 7;

    if (bid < 63) {
        // ---- CPB MLP ----
        float* s1 = (float*)smem;      // 1024 f
        float* sb = s1 + 1024;         // 512 f
        float* s2 = sb + 512;          // 4096 f
        for (int i = tid; i < 1024; i += 256) s1[i] = fc1w[i];
        for (int i = tid; i < 512;  i += 256) sb[i] = fc1b[i];
        for (int i = tid; i < 4096; i += 256) s2[i] = fc2w[i];
        __syncthreads();
        int rl = tid >> 2, jp = tid & 3;
        bool ok = rl < 63;
        int r = bid * 63 + rl;
        float c0 = ok ? rct[2*r]   : 0.f;
        float c1 = ok ? rct[2*r+1] : 0.f;
        float a[8] = {0,0,0,0,0,0,0,0};
        int j0 = jp * 128;
        #pragma unroll 4
        for (int j = j0; j < j0 + 128; ++j) {
            float hv = fmaxf(c0*s1[2*j] + c1*s1[2*j+1] + sb[j], 0.0f);
            #pragma unroll
            for (int hh = 0; hh < 8; ++hh) a[hh] += hv * s2[hh*512 + j];
        }
        #pragma unroll
        for (int hh = 0; hh < 8; ++hh) {
            a[hh] += __shfl_xor(a[hh], 1);
            a[hh] += __shfl_xor(a[hh], 2);
        }
        if (ok && jp == 0) {
            #pragma unroll
            for (int hh = 0; hh < 8; ++hh)
                tblf[hh*3969 + r] = (a[hh] + fc2b[hh]) * LOG2E;  // pre-scaled
        }
    } else if (bid < 95) {
        // ---- proj_w fp32 -> fp16 swizzled ----
        int base8 = (bid - 63) * 256;
        int e0 = (base8 + tid) * 8;
        int m  = e0 >> 8;
        int k  = e0 & 255;
        int kt = k >> 6, c = (k >> 3) & 7;
        float4 f0 = *(const float4*)(wp + e0);
        float4 f1 = *(const float4*)(wp + e0 + 4);
        float v[8] = {f0.x,f0.y,f0.z,f0.w,f1.x,f1.y,f1.z,f1.w};
        v8s hi;
        #pragma unroll
        for (int j = 0; j < 8; ++j) hi[j] = f2h(v[j]);
        int dst = m*256 + kt*64 + ((c ^ (m & 7)) << 3);
        *(v8s*)&wph[dst] = hi;
    } else if (bid < 159) {
        // ---- rpi -> packed u16 index table, biasM fragment order ----
        int q16 = bid - 95;            // 0..63 (16-row group)
        int grp = tid >> 6;            // 0..3
        #pragma unroll 1
        for (int c = 0; c < 16; ++c) {
            int combo = grp*16 + c;
            int kt = combo >> 2, g = combo & 3;
            unsigned long long pk = 0;
            #pragma unroll
            for (int r = 0; r < 4; ++r) {
                int idx = rpi[(size_t)(q16*16 + quad*4 + r)*1024 + kt*64 + 4*t + g];
                pk |= (unsigned long long)(idx & 0xFFFF) << (16*r);
            }
            bi[((size_t)(q16*16 + kt)*4 + g)*64 + lane] = pk;
        }
    } else {
        // ---- qkv GEMM, fp32-staged ----
        short* A0 = (short*)smem;          // [128][64] fp16, k-tile even
        short* A1 = A0 + 128*64;
        short* W0 = A1 + 128*64;           // [64][64]
        short* W1 = W0 + 64*64;
        int g2 = bid - 159;
        int n0 = (g2 % 12) * 64, m0 = (g2 / 12) * 128;
        int Mw = (w >> 1) * 64, Nw = (w & 1) * 32;

        v4f acc[4][2];
        #pragma unroll
        for (int mt = 0; mt < 4; ++mt)
            #pragma unroll
            for (int nt = 0; nt < 2; ++nt) acc[mt][nt] = (v4f){0,0,0,0};

        #pragma unroll 1
        for (int kt2 = 0; kt2 < 2; ++kt2) {
            __syncthreads();
            #pragma unroll
            for (int half = 0; half < 2; ++half) {
                int kt = kt2*2 + half;
                short* Ad = half ? A1 : A0;
                short* Wd = half ? W1 : W0;
                #pragma unroll
                for (int i = 0; i < 4; ++i) {
                    int rr = w*32 + i*8 + lr8;
                    const float* s = x + (size_t)(m0 + rr)*256 + kt*64 + lc8*8;
                    float4 f0 = *(const float4*)s;
                    float4 f1 = *(const float4*)(s + 4);
                    v8h hv;
                    hv[0]=(_Float16)f0.x; hv[1]=(_Float16)f0.y;
                    hv[2]=(_Float16)f0.z; hv[3]=(_Float16)f0.w;
                    hv[4]=(_Float16)f1.x; hv[5]=(_Float16)f1.y;
                    hv[6]=(_Float16)f1.z; hv[7]=(_Float16)f1.w;
                    *(v8h*)&Ad[rr*64 + ((lc8 ^ lr8) << 3)] = hv;   // rr&7 == lr8
                }
                #pragma unroll
                for (int i = 0; i < 2; ++i) {
                    int rr = w*16 + i*8 + lr8;
                    const float* s = wq + (size_t)(n0 + rr)*256 + kt*64 + lc8*8;
                    float4 f0 = *(const float4*)s;
                    float4 f1 = *(const float4*)(s + 4);
                    v8h hv;
                    hv[0]=(_Float16)f0.x; hv[1]=(_Float16)f0.y;
                    hv[2]=(_Float16)f0.z; hv[3]=(_Float16)f0.w;
                    hv[4]=(_Float16)f1.x; hv[5]=(_Float16)f1.y;
                    hv[6]=(_Float16)f1.z; hv[7]=(_Float16)f1.w;
                    *(v8h*)&Wd[rr*64 + ((lc8 ^ lr8) << 3)] = hv;
                }
            }
            __syncthreads();
            #pragma unroll
            for (int half = 0; half < 2; ++half) {
                const short* As = half ? A1 : A0;
                const short* Ws = half ? W1 : W0;
                #pragma unroll
                for (int kk = 0; kk < 2; ++kk) {
                    int cp = ((kk*4 + quad) ^ (t & 7)) << 3;
                    v8h bh8[2];
                    #pragma unroll
                    for (int nt = 0; nt < 2; ++nt)
                        bh8[nt] = *(const v8h*)&Ws[(Nw + nt*16 + t)*64 + cp];
                    #pragma unroll
                    for (int mt = 0; mt < 4; ++mt) {
                        v8h ah = *(const v8h*)&As[(Mw + mt*16 + t)*64 + cp];
                        #pragma unroll
                        for (int nt = 0; nt < 2; ++nt)
                            acc[mt][nt] = MFMAH(ah, bh8[nt], acc[mt][nt]);
                    }
                }
            }
        }

        // bias
        #pragma unroll
        for (int nt = 0; nt < 2; ++nt) {
            float bv = qkvb[n0 + Nw + nt*16 + t];
            #pragma unroll
            for (int mt = 0; mt < 4; ++mt)
                #pragma unroll
                for (int r = 0; r < 4; ++r) acc[mt][nt][r] += bv;
        }

        int which = n0 >> 8;
        if (which < 2) {
            int head = ((n0 + Nw) >> 5) & 7;
            float scale = 0.f;
            if (which == 0)
                scale = log1pf(__expf(temp[head])) * 10.0f;  // softplus*ln(1024)*log2e
            #pragma unroll
            for (int mt = 0; mt < 4; ++mt)
                #pragma unroll
                for (int r = 0; r < 4; ++r) {
                    float a0 = acc[mt][0][r], a1 = acc[mt][1][r];
                    float s = a0*a0 + a1*a1;
                    s += __shfl_xor(s, 1); s += __shfl_xor(s, 2);
                    s += __shfl_xor(s, 4); s += __shfl_xor(s, 8);
                    float inv = 1.0f / fmaxf(sqrtf(s), 1e-12f);
                    int m = m0 + Mw + mt*16 + quad*4 + r;
                    int b = m >> 10, nrow = m & 1023;
                    if (which == 0) {
                        size_t rowoff = (((size_t)b*8 + head)*1024 + nrow) * 32;
                        #pragma unroll
                        for (int nt = 0; nt < 2; ++nt) {
                            int d = nt*16 + t;
                            float val = (acc[mt][nt][r] * inv + qe[head*32 + d]) * scale;
                            qh[rowoff + d] = f2h(val);
                        }
                    } else {
                        int kk = nrow & 63;
                        int pp = (kk & 3)*16 + (kk >> 2);
                        int prow = (nrow & ~63) | pp;
                        int swk = (kk >> 3) & 3;
                        size_t rowoff = (((size_t)b*8 + head)*1024 + prow) * 32;
                        #pragma unroll
                        for (int nt = 0; nt < 2; ++nt) {
                            int d = nt*16 + t;
                            int dpos = (((d >> 3) ^ swk) << 3) | (d & 7);
                            kh[rowoff + dpos] = f2h(acc[mt][nt][r] * inv);
                        }
                    }
                }
        } else {
            // v: transpose via LDS, write vt[bh][dim][key] bf16, tile-swizzled
            __syncthreads();
            short* VT = (short*)smem;        // [64][136]
            #pragma unroll
            for (int mt = 0; mt < 4; ++mt)
                #pragma unroll
                for (int nt = 0; nt < 2; ++nt) {
                    int cl = Nw + nt*16 + t;
                    #pragma unroll
                    for (int r = 0; r < 4; ++r) {
                        int rl = Mw + mt*16 + quad*4 + r;
                        VT[cl*136 + rl] = bf_rh(acc[mt][nt][r]);
                    }
                }
            __syncthreads();
            int b = m0 >> 10;
            int keybase = m0 & 1023;
            int headbase = ((n0 - 512) >> 5) & 7;
            int cl = tid >> 2;
            int dim = cl & 31;
            int hd  = headbase + (cl >> 5);
            size_t obase = (((size_t)b*8 + hd)*32 + dim) * 1024 + keybase;
            #pragma unroll
            for (int pz = 0; pz < 4; ++pz) {
                int ci  = (tid & 3) * 4 + pz;
                int ktl = ci >> 3, c = ci & 7;
                v8s val = *(const v8s*)&VT[cl*136 + ktl*64 + c*8];
                *(v8s*)&vt[obase + ktl*64 + ((c ^ (dim & 7)) << 3)] = val;
            }
        }
    }
}

// ---------------------------------------------------------------------------
// K2 attn: MFMA flash attention, exp2 domain, fp16 QK^T, bf16 PV.
// Q-tile = 128 rows, 8 waves, 512 blocks, double-buffered K/V LDS.
// Bias ON THE FLY: tblf[h] (pre-scaled log2e) staged once in LDS (15.9 KB);
// packed u16 indices loaded with the identical address pattern the old biasM
// used (4 x u64 per lane per tile, register-pipelined), then 16 LDS f32
// gathers form the MFMA C-init. Removes the 16 MB biasM round trip entirely.
// ---------------------------------------------------------------------------
__global__ __launch_bounds__(512)
void attn_mfma(const short* __restrict__ qh, const short* __restrict__ kh,
               const short* __restrict__ vt,
               const unsigned long long* __restrict__ bi,
               const float* __restrict__ tblf,
               short* __restrict__ yh)
{
    __shared__ __align__(16) short Kh_s[2][2048];   // [64][32] fp16
    __shared__ __align__(16) short Vt_s[2][2048];   // [32][64] bf16
    __shared__ __align__(16) short Ps[8][16][68];   // per-wave P (bf16)
    __shared__ float tb[3972];                      // tblf[h] * log2e

    int bh  = blockIdx.x & 63;   // bid%8 == h (XCD-aligned, neutral)
    int qt  = blockIdx.x >> 6;
    int h   = bh & 7;
    int b   = bh >> 3;
    int tid = threadIdx.x;
    int w    = tid >> 6;        // 0..7
    int lane = tid & 63;
    int t    = lane & 15;
    int quad = lane >> 4;

    // stage bias table for this head
    for (int i = tid; i < 3969; i += 512) tb[i] = tblf[h*3969 + i];

    size_t qoff = ((size_t)bh*1024 + qt*128 + w*16 + t) * 32 + quad*8;
    v8h qf = *(const v8h*)(qh + qoff);

    v4f Oacc[2] = {{0,0,0,0},{0,0,0,0}};
    float lsum[4] = {0,0,0,0};

    size_t kgbase = (size_t)bh * 32768;
    const unsigned long long* bmb = bi + (size_t)(qt*8 + w)*4096 + lane;
    int qrow0 = qt*128 + w*16 + quad*4;
    int swzS = (quad ^ ((t >> 1) & 3)) << 3;
    int lr8 = lane >> 3, lc8 = lane & 7;

    // stage tile 0 into buffer 0 (1 gld16 per wave: w<4 -> K, w>=4 -> V)
    if (w < 4)
        gld16(kh + kgbase + w*512 + lane*8, &Kh_s[0][w*512]);
    else
        gld16(vt + kgbase + (size_t)((w-4)*8 + lr8)*1024 + lc8*8, &Vt_s[0][(w-4)*512]);
    unsigned long long curb[4];
    #pragma unroll
    for (int g = 0; g < 4; ++g) curb[g] = bmb[g*64];

    #pragma unroll 1
    for (int kt = 0; kt < 16; ++kt) {
        int cur = kt & 1;
        __syncthreads();   // tile loads landed; tb staged (first iter)
        unsigned long long nxtb[4];
        if (kt < 15) {
            int nkt = kt + 1, nb = cur ^ 1;
            if (w < 4)
                gld16(kh + kgbase + (size_t)nkt*2048 + w*512 + lane*8, &Kh_s[nb][w*512]);
            else
                gld16(vt + kgbase + (size_t)((w-4)*8 + lr8)*1024 + nkt*64 + lc8*8,
                      &Vt_s[nb][(w-4)*512]);
            #pragma unroll
            for (int g = 0; g < 4; ++g) nxtb[g] = bmb[nkt*256 + g*64];
        }

        // S = bias + Q K^T (fp16, 1 pass), exp2 domain; bias gathered from LDS
        v4f S[4];
        #pragma unroll
        for (int g = 0; g < 4; ++g) {
            v8h kb = *(const v8h*)&Kh_s[cur][(g*16 + t)*32 + swzS];
            unsigned long long cb = curb[g];
            v4f c;
            c[0] = tb[(uint32_t)cb & 0xFFFFu];
            c[1] = tb[(uint32_t)(cb >> 16) & 0xFFFFu];
            c[2] = tb[(uint32_t)(cb >> 32) & 0xFFFFu];
            c[3] = tb[(uint32_t)(cb >> 48)];
            S[g] = MFMAH(qf, kb, c);
        }

        // p = exp2(S); P cols are contiguous actual keys 4t+g -> packed b64
        #pragma unroll
        for (int r = 0; r < 4; ++r) {
            float p0 = EXP2(S[0][r]);
            float p1 = EXP2(S[1][r]);
            float p2 = EXP2(S[2][r]);
            float p3 = EXP2(S[3][r]);
            lsum[r] += (p0 + p1) + (p2 + p3);
            uint2 pk;
            pk.x = pack_bf_rh(p0, p1);
            pk.y = pack_bf_rh(p2, p3);
            *(uint2*)&Ps[w][quad*4 + r][t*4] = pk;
        }

        // O += P V (same-wave LDS dependency, no barrier)
        #pragma unroll
        for (int ks = 0; ks < 2; ++ks) {
            v8s pf = *(const v8s*)&Ps[w][t][ks*32 + quad*8];
            int vsw = ((ks*4 + quad) ^ (t & 7)) << 3;
            #pragma unroll
            for (int g = 0; g < 2; ++g) {
                v8s vf = *(const v8s*)&Vt_s[cur][(g*16 + t)*64 + vsw];
                Oacc[g] = MFMA(pf, vf, Oacc[g]);
            }
        }
        #pragma unroll
        for (int g = 0; g < 4; ++g) curb[g] = nxtb[g];
    }

    // epilogue: reduce l, normalize, write swizzled fp16 y
    #pragma unroll
    for (int r = 0; r < 4; ++r) {
        float l = lsum[r];
        l += __shfl_xor(l, 1); l += __shfl_xor(l, 2);
        l += __shfl_xor(l, 4); l += __shfl_xor(l, 8);
        float inv = 1.0f / l;
        int qrow = qrow0 + r;
        int m = b*1024 + qrow;
        size_t mbase = (size_t)m * 256;
        int mk = m & 7;
        #pragma unroll
        for (int g = 0; g < 2; ++g) {
            float o = Oacc[g][r] * inv;
            int c = h*4 + g*2 + (t >> 3);
            int chp = ((c ^ mk) << 3) | (t & 7);
            yh[mbase + chp] = f2h(o);
        }
    }
}

// ---------------------------------------------------------------------------
// K3 output projection: fp16 1-pass MFMA GEMM, TM=64 TN=64, BK=128.
// ---------------------------------------------------------------------------
__global__ __launch_bounds__(256)
void gemm_proj(const short* __restrict__ Ah_g, const short* __restrict__ Wh_g,
               const float* __restrict__ bias, float* __restrict__ C, int N)
{
    __shared__ __align__(16) short As[2][4096];   // [64][64] fp16 per buf
    __shared__ __align__(16) short Ws[2][4096];

    int tid  = threadIdx.x;
    int w    = tid >> 6;
    int lane = tid & 63;
    int t    = lane & 15;
    int quad = lane >> 4;
    int m0 = blockIdx.y * 64, n0 = blockIdx.x * 64;
    int Mw = (w >> 1) * 32, Nw = (w & 1) * 32;

    v4f acc[2][2];
    #pragma unroll
    for (int mt = 0; mt < 2; ++mt)
        #pragma unroll
        for (int nt = 0; nt < 2; ++nt) acc[mt][nt] = (v4f){0,0,0,0};

    int lr8 = lane >> 3, lc8 = lane & 7;
    #pragma unroll 1
    for (int kt2 = 0; kt2 < 2; ++kt2) {
        __syncthreads();
        #pragma unroll
        for (int half = 0; half < 2; ++half) {
            int kt = kt2*2 + half;
            #pragma unroll
            for (int i = 0; i < 2; ++i) {
                size_t grow = (size_t)(m0 + w*16 + i*8 + lr8) * 256 + kt*64 + lc8*8;
                gld16(Ah_g + grow, &As[half][(w*16 + i*8) * 64]);
            }
            #pragma unroll
            for (int i = 0; i < 2; ++i) {
                size_t grow = (size_t)(n0 + w*16 + i*8 + lr8) * 256 + kt*64 + lc8*8;
                gld16(Wh_g + grow, &Ws[half][(w*16 + i*8) * 64]);
            }
        }
        __syncthreads();
        #pragma unroll
        for (int half = 0; half < 2; ++half) {
            #pragma unroll
            for (int kk = 0; kk < 2; ++kk) {
                int cp = ((kk*4 + quad) ^ (t & 7)) << 3;
                v8h bh8[2];
                #pragma unroll
                for (int nt = 0; nt < 2; ++nt)
                    bh8[nt] = *(const v8h*)&Ws[half][(Nw + nt*16 + t)*64 + cp];
                #pragma unroll
                for (int mt = 0; mt < 2; ++mt) {
                    v8h ah = *(const v8h*)&As[half][(Mw + mt*16 + t)*64 + cp];
                    #pragma unroll
                    for (int nt = 0; nt < 2; ++nt)
                        acc[mt][nt] = MFMAH(ah, bh8[nt], acc[mt][nt]);
                }
            }
        }
    }

    #pragma unroll
    for (int nt = 0; nt < 2; ++nt) {
        float bv = bias[n0 + Nw + nt*16 + t];
        #pragma unroll
        for (int mt = 0; mt < 2; ++mt)
            #pragma unroll
            for (int r = 0; r < 4; ++r) acc[mt][nt][r] += bv;
    }
    #pragma unroll
    for (int mt = 0; mt < 2; ++mt)
        #pragma unroll
        for (int r = 0; r < 4; ++r) {
            int m = m0 + Mw + mt*16 + quad*4 + r;
            #pragma unroll
            for (int nt = 0; nt < 2; ++nt)
                C[(size_t)m * N + n0 + Nw + nt*16 + t] = acc[mt][nt][r];
        }
}

// ---------------------------------------------------------------------------
extern "C" void kernel_launch(void* const* d_in, const int* in_sizes, int n_in,
                              void* d_out, int out_size, void* d_ws, size_t ws_size,
                              hipStream_t stream)
{
    const float* x     = (const float*)d_in[0];
    const int*   rpi   = (const int*)d_in[3];
    const float* rct   = (const float*)d_in[4];
    const float* qkvw  = (const float*)d_in[5];
    const float* qkvb  = (const float*)d_in[6];
    const float* qe    = (const float*)d_in[7];
    const float* temp  = (const float*)d_in[8];
    const float* projw = (const float*)d_in[9];
    const float* projb = (const float*)d_in[10];
    const float* fc1w  = (const float*)d_in[11];
    const float* fc1b  = (const float*)d_in[12];
    const float* fc2w  = (const float*)d_in[13];
    const float* fc2b  = (const float*)d_in[14];

    char* p = (char*)d_ws;
    float* tblf  = (float*)p;  p += 131072;
    short* y     = (short*)p;  p += 4194304;   // attn output (fp16, swizzled)
    short* wph   = (short*)p;  p += 131072;
    short* qh    = (short*)p;  p += 4194304;
    short* kh    = (short*)p;  p += 4194304;
    short* vt    = (short*)p;  p += 4194304;
    unsigned long long* bi = (unsigned long long*)p; p += 2097152;
    float* out   = (float*)d_out;

    // 1) fused: qkv GEMM (fp32-staged) + CPB MLP + wp convert + rpi pack
    fused_qkv<<<927, 256, 0, stream>>>(x, qkvw, projw, rct,
                                       fc1w, fc1b, fc2w, fc2b,
                                       qkvb, qe, temp, rpi,
                                       qh, kh, vt, tblf, wph, bi);

    // 2) attention with on-the-fly LDS bias gather -> fp16 y
    attn_mfma<<<512, 512, 0, stream>>>(qh, kh, vt, bi, tblf, y);

    // 3) output projection -> d_out (fp32)
    dim3 g2(256/64, 8192/64);
    gemm_proj<<<g2, 256, 0, stream>>>(y, wph, projb, out, 256);
}